// Round 8
// baseline (31.890 us; speedup 1.0000x reference)
//
#include <hip/hip_runtime.h>

#define NB 4096
#define T_FRAMES 8192
#define T_TOKENS 2048
#define NTHREADS 1024
#define FPT 8                     // frames per thread (8 * 1024 = 8192)
#define TPT 2                     // tokens per thread (2 * 1024 = 2048)
#define NWAVES (NTHREADS / 64)    // 16
#define PADSLOT(i) ((i) + ((i) >> 4))   // +1 pad every 16 slots -> conflict-free

__global__ __launch_bounds__(NTHREADS, 8) void avg_by_dur_kernel(
    const float* __restrict__ frame_scalar,
    const int*   __restrict__ frame_len,
    const int*   __restrict__ duration,
    const int*   __restrict__ duration_len,
    float*       __restrict__ out)
{
    __shared__ float s_pref[PADSLOT(T_FRAMES) + 8];  // 8712 floats ≈ 34 KB
    __shared__ float s_fsum[NWAVES];
    __shared__ int   s_wsum[NWAVES];

    const int row  = blockIdx.x;
    const int t    = threadIdx.x;
    const int lane = t & 63;
    const int wid  = t >> 6;

    const int L    = frame_len[row];
    const int dlen = duration_len[row];

    if (t == 0) out[(size_t)NB * T_TOKENS + row] = (float)dlen;  // output 1

    // ---- coalesced frame loads: 8 contiguous floats per thread (2 float4)
    // Elements beyond L are real (allocated) data; they only influence prefix
    // slots > L, which are never read.
    float f[FPT];
    {
        const float4* g4 = reinterpret_cast<const float4*>(
            frame_scalar + (size_t)row * T_FRAMES) + t * 2;
        float4 a = make_float4(0.f, 0.f, 0.f, 0.f);
        float4 b = a;
        if (t * FPT < L) { a = g4[0]; b = g4[1]; }
        f[0] = a.x; f[1] = a.y; f[2] = a.z; f[3] = a.w;
        f[4] = b.x; f[5] = b.y; f[6] = b.z; f[7] = b.w;
    }

    // ---- durations for this thread's 2 tokens
    int v0 = 0, v1 = 0;
    {
        const int j0 = t * TPT;
        if (j0 < dlen) {
            const int2 dd = reinterpret_cast<const int2*>(
                duration + (size_t)row * T_TOKENS)[t];
            v0 = dd.x > 0 ? dd.x : 0;
            v1 = (j0 + 1 < dlen) ? (dd.y > 0 ? dd.y : 0) : 0;
        }
    }
    const int run = v0 + v1;

    // ---- local inclusive scan of the 8 frame values
    #pragma unroll
    for (int j = 1; j < FPT; ++j) f[j] += f[j - 1];
    const float ftot = f[FPT - 1];

    // ---- wave scans: int (durations) and f32 (frames), no barriers
    int x = run;
    float y = ftot;
    #pragma unroll
    for (int off = 1; off < 64; off <<= 1) {
        int   xi = __shfl_up(x, off, 64);
        float yi = __shfl_up(y, off, 64);
        if (lane >= off) { x += xi; y += yi; }
    }
    if (lane == 63) { s_wsum[wid] = x; s_fsum[wid] = y; }

    // ---- barrier 1: publish wave totals
    __syncthreads();

    int   dbase = x - run;    // exclusive within wave
    float fbase = y - ftot;
    #pragma unroll
    for (int w = 0; w < NWAVES; ++w) {
        if (w < wid) { dbase += s_wsum[w]; fbase += s_fsum[w]; }
    }

    // ---- write padded prefix slots (skip threads whose slots are never read)
    if (t * FPT < L) {
        #pragma unroll
        for (int j = 0; j < FPT; ++j) {
            const int idx = t * FPT + j + 1;
            s_pref[PADSLOT(idx)] = fbase + f[j];
        }
    }
    if (t == 0) s_pref[0] = 0.0f;

    // ---- barrier 2: prefix visible
    __syncthreads();

    // ---- token means via prefix differences (3 boundary reads per thread)
    const int s0 = dbase            < L ? dbase            : L;
    const int e0 = (dbase + v0)     < L ? (dbase + v0)     : L;
    const int e1 = (dbase + run)    < L ? (dbase + run)    : L;
    const float Ps = s_pref[PADSLOT(s0)];
    const float P0 = s_pref[PADSLOT(e0)];
    const float P1 = s_pref[PADSLOT(e1)];

    const int j0 = t * TPT;
    const int l0 = e0 - s0;
    const int l1 = e1 - e0;
    float o0 = 0.0f, o1 = 0.0f;
    if (l0 > 0 && j0 < dlen)     o0 = (P0 - Ps) / (float)l0;
    if (l1 > 0 && j0 + 1 < dlen) o1 = (P1 - P0) / (float)l1;

    reinterpret_cast<float2*>(out + (size_t)row * T_TOKENS)[t] = make_float2(o0, o1);
}

extern "C" void kernel_launch(void* const* d_in, const int* in_sizes, int n_in,
                              void* d_out, int out_size, void* d_ws, size_t ws_size,
                              hipStream_t stream) {
    const float* frame_scalar     = (const float*)d_in[0];
    const int*   frame_scalar_len = (const int*)d_in[1];
    const int*   duration         = (const int*)d_in[2];
    const int*   duration_len     = (const int*)d_in[3];
    float* out = (float*)d_out;

    avg_by_dur_kernel<<<NB, NTHREADS, 0, stream>>>(
        frame_scalar, frame_scalar_len, duration, duration_len, out);
}

// Round 9
// 29.537 us; speedup vs baseline: 1.0797x; 1.0797x over previous
//
#include <hip/hip_runtime.h>

#define NB 4096
#define T_FRAMES 8192
#define T_TOKENS 2048
#define NTHREADS 512
#define TPT (T_TOKENS / NTHREADS)   // 4 tokens per thread
#define NWAVES (NTHREADS / 64)      // 8
#define MAX_DUR_M1 7                // durations in [0, 8)
#define TOTAL4 (T_FRAMES / 4)       // 2048 float4 per row
#define ALL_ROUNDS (TOTAL4 / NTHREADS)  // 4 staging rounds total
#define SPEC_ROUNDS 2               // first 4096 floats staged pre-scan (L >= 4096 always)

__device__ __forceinline__ void load_lds16(const float4* g, float4* l) {
    __builtin_amdgcn_global_load_lds(
        (const __attribute__((address_space(1))) void*)g,
        (__attribute__((address_space(3))) void*)l,
        16, 0, 0);
}

__global__ __launch_bounds__(NTHREADS, 8) void avg_by_dur_kernel(
    const float* __restrict__ frame_scalar,
    const int*   __restrict__ frame_len,
    const int*   __restrict__ duration,
    const int*   __restrict__ duration_len,
    float*       __restrict__ out)
{
    __shared__ float s_frame[T_FRAMES];   // 32 KB staged frame prefix
    __shared__ int   s_wsum[NWAVES];

    const int row  = blockIdx.x;
    const int t    = threadIdx.x;
    const int lane = t & 63;
    const int wid  = t >> 6;

    const int L    = frame_len[row];
    const int dlen = duration_len[row];

    // ---- output 1 early
    if (t == 0) {
        out[(size_t)NB * T_TOKENS + row] = (float)dlen;
    }

    // ---- duration load FIRST (oldest VMEM op: the scan's dependent wait
    // becomes vmcnt(2) and does NOT drain the staging loads issued below)
    int d[TPT] = {0, 0, 0, 0};
    if (t * TPT < dlen) {
        const int4 a = reinterpret_cast<const int4*>(duration + (size_t)row * T_TOKENS)[t];
        d[0] = a.x; d[1] = a.y; d[2] = a.z; d[3] = a.w;
    }

    // ---- speculative staging of frames [0, 4096) before the scan.
    // L >= T_FRAMES/2 = 4096 always, so these addresses are valid and the
    // bytes are needed whenever needed >= 4096 (~85% of rows; tiny harmless
    // over-fetch otherwise). Overlaps dur-load latency + scan with staging.
    const float4* frow = reinterpret_cast<const float4*>(frame_scalar + (size_t)row * T_FRAMES);
    float4* lrow = reinterpret_cast<float4*>(s_frame);
    #pragma unroll
    for (int i = 0; i < SPEC_ROUNDS; ++i) {
        const int p = t + i * NTHREADS;
        load_lds16(frow + p, lrow + p);
    }

    // ---- per-thread duration prefix
    int incl[TPT];
    int run = 0;
    #pragma unroll
    for (int k = 0; k < TPT; ++k) {
        int v = d[k] > 0 ? d[k] : 0;
        run += v;
        incl[k] = run;
    }

    // ---- wave-level inclusive scan
    int x = run;
    #pragma unroll
    for (int off = 1; off < 64; off <<= 1) {
        int y = __shfl_up(x, off, 64);
        if (lane >= off) x += y;
    }
    if (lane == 63) s_wsum[wid] = x;

    // ---- barrier 1: publish wave sums
    __syncthreads();

    int wbase = 0;
    int total = 0;
    #pragma unroll
    for (int w = 0; w < NWAVES; ++w) {
        const int s = s_wsum[w];
        total += s;
        if (w < wid) wbase += s;
    }
    const int base = wbase + (x - run);

    // ---- exact remaining staging: frames [4096, needed)
    const int needed  = total < L ? total : L;
    const int needed4 = (needed + 3) >> 2;
    #pragma unroll
    for (int i = SPEC_ROUNDS; i < ALL_ROUNDS; ++i) {
        const int p = t + i * NTHREADS;
        if (p < needed4) load_lds16(frow + p, lrow + p);
    }

    // ---- barrier 2: drains all staging (vmcnt(0) + s_barrier)
    __syncthreads();

    // ---- per-token segment means from LDS
    float outv[TPT];
    int start = base < L ? base : L;
    #pragma unroll
    for (int k = 0; k < TPT; ++k) {
        int e = base + incl[k];
        if (e > L) e = L;
        const int j = t * TPT + k;
        const int len = e - start;
        float r = 0.0f;
        if (len > 0 && j < dlen) {
            float s = 0.0f;
            #pragma unroll
            for (int q = 0; q < MAX_DUR_M1; ++q) {
                const int idx = start + q;
                const float v = s_frame[idx < e ? idx : start];
                if (idx < e) s += v;
            }
            r = s / (float)len;
        }
        outv[k] = r;
        start = e;
    }

    // ---- coalesced store: one float4 per thread
    reinterpret_cast<float4*>(out + (size_t)row * T_TOKENS)[t] =
        make_float4(outv[0], outv[1], outv[2], outv[3]);
}

extern "C" void kernel_launch(void* const* d_in, const int* in_sizes, int n_in,
                              void* d_out, int out_size, void* d_ws, size_t ws_size,
                              hipStream_t stream) {
    const float* frame_scalar     = (const float*)d_in[0];
    const int*   frame_scalar_len = (const int*)d_in[1];
    const int*   duration         = (const int*)d_in[2];
    const int*   duration_len     = (const int*)d_in[3];
    float* out = (float*)d_out;

    avg_by_dur_kernel<<<NB, NTHREADS, 0, stream>>>(
        frame_scalar, frame_scalar_len, duration, duration_len, out);
}

// Round 10
// 27.569 us; speedup vs baseline: 1.1567x; 1.0714x over previous
//
#include <hip/hip_runtime.h>

#define NB 4096
#define T_FRAMES 8192
#define T_TOKENS 2048
#define NTHREADS 512
#define TPT (T_TOKENS / NTHREADS)   // 4 tokens per thread
#define NWAVES (NTHREADS / 64)      // 8
#define MAX_DUR_M1 7                // durations in [0, 8)

__device__ __forceinline__ void load_lds16(const float4* g, float4* l) {
    __builtin_amdgcn_global_load_lds(
        (const __attribute__((address_space(1))) void*)g,
        (__attribute__((address_space(3))) void*)l,
        16, 0, 0);
}

__global__ __launch_bounds__(NTHREADS, 8) void avg_by_dur_kernel(
    const float* __restrict__ frame_scalar,
    const int*   __restrict__ frame_len,
    const int*   __restrict__ duration,
    const int*   __restrict__ duration_len,
    float*       __restrict__ out)
{
    __shared__ float s_frame[T_FRAMES];   // 32 KB staged frame prefix
    __shared__ int   s_wsum[NWAVES];

    const int row  = blockIdx.x;
    const int t    = threadIdx.x;
    const int lane = t & 63;
    const int wid  = t >> 6;

    const int L    = frame_len[row];
    const int dlen = duration_len[row];

    // ---- output 1 early (independent of everything else)
    if (t == 0) {
        out[(size_t)NB * T_TOKENS + row] = (float)dlen;
    }

    // ---- durations for this thread's 4 tokens (one int4; skip if all >= dlen)
    int d[TPT] = {0, 0, 0, 0};
    if (t * TPT < dlen) {
        const int4 a = reinterpret_cast<const int4*>(duration + (size_t)row * T_TOKENS)[t];
        d[0] = a.x; d[1] = a.y; d[2] = a.z; d[3] = a.w;
    }
    int incl[TPT];
    int run = 0;
    #pragma unroll
    for (int k = 0; k < TPT; ++k) {
        int v = d[k] > 0 ? d[k] : 0;
        run += v;
        incl[k] = run;
    }

    // ---- wave-level inclusive scan of per-thread sums
    int x = run;
    #pragma unroll
    for (int off = 1; off < 64; off <<= 1) {
        int y = __shfl_up(x, off, 64);
        if (lane >= off) x += y;
    }
    if (lane == 63) s_wsum[wid] = x;

    // ---- barrier 1: publish wave sums
    __syncthreads();

    int wbase = 0;
    int total = 0;
    #pragma unroll
    for (int w = 0; w < NWAVES; ++w) {
        const int s = s_wsum[w];
        total += s;
        if (w < wid) wbase += s;
    }
    const int base = wbase + (x - run);   // exclusive prefix over all prior tokens

    // Exact frame span touched by valid tokens: [0, min(total_csum, L)).
    const int needed  = total < L ? total : L;
    const int needed4 = (needed + 3) >> 2;

    // ---- async global->LDS staging of exactly the needed frame prefix
    const float4* frow = reinterpret_cast<const float4*>(frame_scalar + (size_t)row * T_FRAMES);
    float4* lrow = reinterpret_cast<float4*>(s_frame);
    #pragma unroll
    for (int i = 0; i < T_FRAMES / 4 / NTHREADS; ++i) {   // 4 predicated 16B loads
        const int p = t + i * NTHREADS;
        if (p < needed4) load_lds16(frow + p, lrow + p);
    }

    // ---- barrier 2: drains global_load_lds (compiler emits vmcnt(0) before s_barrier)
    __syncthreads();

    // ---- per-token segment means from LDS
    float outv[TPT];
    int start = base < L ? base : L;
    #pragma unroll
    for (int k = 0; k < TPT; ++k) {
        int e = base + incl[k];
        if (e > L) e = L;
        const int j = t * TPT + k;
        const int len = e - start;
        float r = 0.0f;
        if (len > 0 && j < dlen) {
            float s = 0.0f;
            #pragma unroll
            for (int q = 0; q < MAX_DUR_M1; ++q) {
                const int idx = start + q;
                const float v = s_frame[idx < e ? idx : start];
                if (idx < e) s += v;
            }
            r = s / (float)len;
        }
        outv[k] = r;
        start = e;
    }

    // ---- coalesced store: one float4 per thread
    reinterpret_cast<float4*>(out + (size_t)row * T_TOKENS)[t] =
        make_float4(outv[0], outv[1], outv[2], outv[3]);
}

extern "C" void kernel_launch(void* const* d_in, const int* in_sizes, int n_in,
                              void* d_out, int out_size, void* d_ws, size_t ws_size,
                              hipStream_t stream) {
    const float* frame_scalar     = (const float*)d_in[0];
    const int*   frame_scalar_len = (const int*)d_in[1];
    const int*   duration         = (const int*)d_in[2];
    const int*   duration_len     = (const int*)d_in[3];
    float* out = (float*)d_out;

    avg_by_dur_kernel<<<NB, NTHREADS, 0, stream>>>(
        frame_scalar, frame_scalar_len, duration, duration_len, out);
}